// Round 2
// baseline (86.600 us; speedup 1.0000x reference)
//
#include <hip/hip_runtime.h>
#include <math.h>

#define N 512
#define BATCH 256
#define KTOP 16
#define NLAYERS 45
#define NPAIRS 256

// One workgroup (1024 threads = 16 waves) per batch element.
//
// Forward: thread-per-element (512 active), x in ping-pong LDS buffers
//   (1 barrier/layer), own value carried in a register (1 partner LDS
//   read/layer). alpha per pair stored to As[t][pair_ordinal] (46 KB LDS).
//
// Backward: out row kk = row (511-kk) of L45*...*L1*I; propagate the one-hot
//   row vector through layers in reverse. Per-pair matrix is symmetric, so
//   v[i] = al*v[i] + (1-al)*v[i^j] with the pair's alpha for BOTH elements.
//   One wave per row, 8 floats/lane (element i at lane i>>3, slot i&7):
//   j>=8 -> __shfl_xor by j>>3; j<8 -> in-register slot swap.
//   Alpha loads vectorize: for lg>=3 the 8 pair-ordinals of a lane are
//   consecutive starting at a multiple of 8 (two ds_read_b128); for lg<3
//   a lane needs only the float4 at As[t][lane*4].
__global__ __launch_bounds__(1024, 1)
void difftopk_kernel(const float* __restrict__ x_in, float* __restrict__ out) {
    __shared__ float xs[2][N];
    __shared__ __align__(16) float As[NLAYERS][NPAIRS];

    const int b   = blockIdx.x;
    const int tid = threadIdx.x;

    // ---------------- forward ----------------
    float o = 0.0f;
    if (tid < N) {
        o = x_in[(size_t)b * N + tid];
        xs[0][tid] = o;
    }
    __syncthreads();

    int cur = 0;
    int t = 0;
    #pragma unroll 1
    for (int s = 1; s <= 9; ++s) {
        const int k = 1 << s;
        #pragma unroll 1
        for (int lg = s - 1; lg >= 0; --lg, ++t) {
            if (tid < N) {
                const int e = tid;
                const int j = 1 << lg;
                const float p = xs[cur][e ^ j];
                // e is the "left" element iff ((e&k)==0) == ((e&j)==0)
                const bool left = ((e & k) == 0) == ((e & j) == 0);
                const float d = left ? (p - o) : (o - p);   // c - a, identical on both pair threads
                const float alpha = atanf(d * 10.0f) * 0.3183098861837907f + 0.5f;
                o = alpha * o + (1.0f - alpha) * p;         // new own value (same form for l and r)
                xs[cur ^ 1][e] = o;
                if ((e & j) == 0) {
                    const int ord = ((e >> (lg + 1)) << lg) | (e & (j - 1));
                    As[t][ord] = alpha;
                }
            }
            cur ^= 1;
            __syncthreads();
        }
    }

    // ---------------- backward ----------------
    const int wave  = tid >> 6;        // 0..15 -> output row kk = wave
    const int lane  = tid & 63;
    const int lane8 = lane << 3;
    const int r     = N - 1 - wave;    // out[b,kk,:] = X[b, 511-kk, :]

    float v[8];
    #pragma unroll
    for (int m = 0; m < 8; ++m) v[m] = (lane8 + m == r) ? 1.0f : 0.0f;

    #pragma unroll 1
    for (int s = 9; s >= 1; --s) {
        const int base = (s * (s - 1)) >> 1;
        #pragma unroll 1
        for (int lg = 0; lg < s; ++lg) {
            const int tt = base + (s - 1 - lg);
            if (lg >= 3) {
                const int j    = 1 << lg;
                const int ordb = ((lane8 >> (lg + 1)) << lg) | (lane8 & (j - 1)); // multiple of 8
                const float4 a0 = *(const float4*)&As[tt][ordb];
                const float4 a1 = *(const float4*)&As[tt][ordb + 4];
                float al[8] = {a0.x, a0.y, a0.z, a0.w, a1.x, a1.y, a1.z, a1.w};
                const int lm = j >> 3;
                float part[8];
                #pragma unroll
                for (int m = 0; m < 8; ++m) part[m] = __shfl_xor(v[m], lm, 64);
                #pragma unroll
                for (int m = 0; m < 8; ++m)
                    v[m] = al[m] * v[m] + (1.0f - al[m]) * part[m];
            } else {
                const float4 a = *(const float4*)&As[tt][lane << 2];
                const float aa[4] = {a.x, a.y, a.z, a.w};
                float nv[8];
                if (lg == 2) {
                    #pragma unroll
                    for (int m = 0; m < 8; ++m) {
                        const float al = aa[m & 3];
                        nv[m] = al * v[m] + (1.0f - al) * v[m ^ 4];
                    }
                } else if (lg == 1) {
                    #pragma unroll
                    for (int m = 0; m < 8; ++m) {
                        const float al = aa[((m >> 2) << 1) | (m & 1)];
                        nv[m] = al * v[m] + (1.0f - al) * v[m ^ 2];
                    }
                } else {
                    #pragma unroll
                    for (int m = 0; m < 8; ++m) {
                        const float al = aa[m >> 1];
                        nv[m] = al * v[m] + (1.0f - al) * v[m ^ 1];
                    }
                }
                #pragma unroll
                for (int m = 0; m < 8; ++m) v[m] = nv[m];
            }
        }
    }

    // ---------------- write out[b, wave, :] ----------------
    float4* dst = (float4*)(out + ((size_t)b * KTOP + wave) * N + lane8);
    dst[0] = make_float4(v[0], v[1], v[2], v[3]);
    dst[1] = make_float4(v[4], v[5], v[6], v[7]);
}

extern "C" void kernel_launch(void* const* d_in, const int* in_sizes, int n_in,
                              void* d_out, int out_size, void* d_ws, size_t ws_size,
                              hipStream_t stream) {
    const float* x = (const float*)d_in[0];
    float* out = (float*)d_out;
    difftopk_kernel<<<dim3(BATCH), dim3(1024), 0, stream>>>(x, out);
}

// Round 3
// 78.744 us; speedup vs baseline: 1.0998x; 1.0998x over previous
//
#include <hip/hip_runtime.h>
#include <math.h>

#define N 512
#define BATCH 256
#define KTOP 16
#define NLAYERS 45
#define NPAIRS 256

// alpha = atan(t)/pi + 0.5 via minimax odd poly (deg 11) + rcp range
// reduction. |err| ~1e-7 in alpha; output threshold is 1.2e-2.
__device__ __forceinline__ float fast_alpha(float t) {
    const float at  = __builtin_fabsf(t);
    const bool inv  = at > 1.0f;
    const float z   = inv ? __builtin_amdgcn_rcpf(at) : at;
    const float s   = z * z;
    float p = -0.0117212f;
    p = __builtin_fmaf(p, s,  0.05265332f);
    p = __builtin_fmaf(p, s, -0.11643287f);
    p = __builtin_fmaf(p, s,  0.19354346f);
    p = __builtin_fmaf(p, s, -0.33262347f);
    p = __builtin_fmaf(p, s,  0.99997726f);
    float r = z * p;
    r = inv ? (1.5707963267948966f - r) : r;
    r = (t < 0.0f) ? -r : r;
    return __builtin_fmaf(r, 0.3183098861837907f, 0.5f);
}

// One 512-thread block (8 waves) per batch element.
//
// Forward: element i lives on lane (i&63) of wave (i>>6) in a register.
//   Compare distance j<64  -> intra-wave __shfl_xor, NO barrier, NO LDS
//   (39 of 45 layers). j in {64,128,256} -> ping-pong LDS + 1 barrier
//   (6 layers). Alphas stored to As[t][pair_ordinal] (45 KB LDS).
//
// Backward: out row kk = row (511-kk) of L45*...*L1*I; propagate one-hot
//   row vectors through layers in reverse (per-pair matrix is symmetric, so
//   the update form is identical to forward). 8 waves x 2 rows/wave,
//   element i at (lane=i>>3, slot=i&7): j>=8 -> shfl_xor by j>>3; j<8 ->
//   in-register slot swap. Alpha float4 loads shared by both rows.
__global__ __launch_bounds__(512, 2)
void difftopk_kernel(const float* __restrict__ x_in, float* __restrict__ out) {
    __shared__ float xs[2][N];
    __shared__ __align__(16) float As[NLAYERS][NPAIRS];

    const int b    = blockIdx.x;
    const int e    = threadIdx.x;   // element 0..511
    const int lane = e & 63;

    // ---------------- forward ----------------
    float o = x_in[(size_t)b * N + e];

    int t = 0, par = 0;
    #pragma unroll 1
    for (int s = 1; s <= 9; ++s) {
        const int k  = 1 << s;
        const bool kb = (e & k) == 0;
        #pragma unroll 1
        for (int lg = s - 1; lg >= 0; --lg, ++t) {
            const int j = 1 << lg;
            float p;
            if (lg >= 6) {              // cross-wave: LDS ping-pong
                xs[par][e] = o;
                __syncthreads();
                p = xs[par][e ^ j];
                par ^= 1;
            } else {                    // intra-wave
                p = __shfl_xor(o, j, 64);
            }
            const bool jb = (e & j) == 0;
            const float d = (kb == jb) ? (p - o) : (o - p);   // c - a
            const float alpha = fast_alpha(d * 10.0f);
            o = __builtin_fmaf(alpha, o - p, p);              // alpha*o+(1-alpha)*p
            if (jb) {
                const int ord = ((e >> (lg + 1)) << lg) | (e & (j - 1));
                As[t][ord] = alpha;
            }
        }
    }
    __syncthreads();   // publish all alphas

    // ---------------- backward ----------------
    const int wave  = e >> 6;          // 0..7 -> rows kk = wave, wave+8
    const int lane8 = lane << 3;
    const int r0 = N - 1 - wave;
    const int r1 = N - 1 - (wave + 8);

    float v0[8], v1[8];
    #pragma unroll
    for (int m = 0; m < 8; ++m) {
        v0[m] = (lane8 + m == r0) ? 1.0f : 0.0f;
        v1[m] = (lane8 + m == r1) ? 1.0f : 0.0f;
    }

    #pragma unroll 1
    for (int s = 9; s >= 1; --s) {
        const int base = (s * (s - 1)) >> 1;
        #pragma unroll 1
        for (int lg = 0; lg < s; ++lg) {
            const int tt = base + (s - 1 - lg);
            if (lg >= 3) {
                const int j    = 1 << lg;
                const int ordb = ((lane8 >> (lg + 1)) << lg) | (lane8 & (j - 1));
                const float4 a0 = *(const float4*)&As[tt][ordb];
                const float4 a1 = *(const float4*)&As[tt][ordb + 4];
                const float al[8] = {a0.x, a0.y, a0.z, a0.w, a1.x, a1.y, a1.z, a1.w};
                const int lm = j >> 3;
                #pragma unroll
                for (int m = 0; m < 8; ++m) {
                    const float p0 = __shfl_xor(v0[m], lm, 64);
                    const float p1 = __shfl_xor(v1[m], lm, 64);
                    v0[m] = __builtin_fmaf(al[m], v0[m] - p0, p0);
                    v1[m] = __builtin_fmaf(al[m], v1[m] - p1, p1);
                }
            } else {
                const float4 a = *(const float4*)&As[tt][lane << 2];
                const float aa[4] = {a.x, a.y, a.z, a.w};
                float n0[8], n1[8];
                if (lg == 2) {
                    #pragma unroll
                    for (int m = 0; m < 8; ++m) {
                        const float al = aa[m & 3];
                        n0[m] = __builtin_fmaf(al, v0[m] - v0[m ^ 4], v0[m ^ 4]);
                        n1[m] = __builtin_fmaf(al, v1[m] - v1[m ^ 4], v1[m ^ 4]);
                    }
                } else if (lg == 1) {
                    #pragma unroll
                    for (int m = 0; m < 8; ++m) {
                        const float al = aa[((m >> 2) << 1) | (m & 1)];
                        n0[m] = __builtin_fmaf(al, v0[m] - v0[m ^ 2], v0[m ^ 2]);
                        n1[m] = __builtin_fmaf(al, v1[m] - v1[m ^ 2], v1[m ^ 2]);
                    }
                } else {
                    #pragma unroll
                    for (int m = 0; m < 8; ++m) {
                        const float al = aa[m >> 1];
                        n0[m] = __builtin_fmaf(al, v0[m] - v0[m ^ 1], v0[m ^ 1]);
                        n1[m] = __builtin_fmaf(al, v1[m] - v1[m ^ 1], v1[m ^ 1]);
                    }
                }
                #pragma unroll
                for (int m = 0; m < 8; ++m) { v0[m] = n0[m]; v1[m] = n1[m]; }
            }
        }
    }

    // ---------------- write out ----------------
    float4* dst0 = (float4*)(out + ((size_t)b * KTOP + wave) * N + lane8);
    dst0[0] = make_float4(v0[0], v0[1], v0[2], v0[3]);
    dst0[1] = make_float4(v0[4], v0[5], v0[6], v0[7]);
    float4* dst1 = (float4*)(out + ((size_t)b * KTOP + wave + 8) * N + lane8);
    dst1[0] = make_float4(v1[0], v1[1], v1[2], v1[3]);
    dst1[1] = make_float4(v1[4], v1[5], v1[6], v1[7]);
}

extern "C" void kernel_launch(void* const* d_in, const int* in_sizes, int n_in,
                              void* d_out, int out_size, void* d_ws, size_t ws_size,
                              hipStream_t stream) {
    const float* x = (const float*)d_in[0];
    float* out = (float*)d_out;
    difftopk_kernel<<<dim3(BATCH), dim3(512), 0, stream>>>(x, out);
}